// Round 4
// baseline (352.832 us; speedup 1.0000x reference)
//
#include <hip/hip_runtime.h>
#include <hip/hip_bf16.h>

#define B     32
#define DIM   4096
#define NH    32
#define NKV   8
#define HD    128
#define TCACHE 2048
#define NREP  4
#define SPLIT 8
#define TS    256   // positions per attention block
#define CHUNK 256   // k-chunk width for projection GEMMs

// ---------------------------------------------------------------------------
// Butterfly reduce-scatter over a wave: input v[64] per-lane partials for 64
// pairs; output: lane L returns the full sum for pair L. 63 shuffles total.
// ---------------------------------------------------------------------------
__device__ __forceinline__ float rs64(float (&v)[64]) {
    const int lane = threadIdx.x & 63;
    float w32[32];
#pragma unroll
    for (int j = 0; j < 32; ++j) {
        const bool up = lane & 32;
        float send = up ? v[j] : v[j + 32];
        float r = __shfl_xor(send, 32);
        w32[j] = (up ? v[j + 32] : v[j]) + r;
    }
    float w16[16];
#pragma unroll
    for (int j = 0; j < 16; ++j) {
        const bool up = lane & 16;
        float send = up ? w16[0] : w16[0]; // placeholder avoided below
        send = up ? w32[j] : w32[j + 16];
        float r = __shfl_xor(send, 16);
        w16[j] = (up ? w32[j + 16] : w32[j]) + r;
    }
    float w8[8];
#pragma unroll
    for (int j = 0; j < 8; ++j) {
        const bool up = lane & 8;
        float send = up ? w16[j] : w16[j + 8];
        float r = __shfl_xor(send, 8);
        w8[j] = (up ? w16[j + 8] : w16[j]) + r;
    }
    float w4[4];
#pragma unroll
    for (int j = 0; j < 4; ++j) {
        const bool up = lane & 4;
        float send = up ? w8[j] : w8[j + 4];
        float r = __shfl_xor(send, 4);
        w4[j] = (up ? w8[j + 4] : w8[j]) + r;
    }
    float w2[2];
#pragma unroll
    for (int j = 0; j < 2; ++j) {
        const bool up = lane & 2;
        float send = up ? w4[j] : w4[j + 2];
        float r = __shfl_xor(send, 2);
        w2[j] = (up ? w4[j + 2] : w4[j]) + r;
    }
    {
        const bool up = lane & 1;
        float send = up ? w2[0] : w2[1];
        float r = __shfl_xor(send, 1);
        return (up ? w2[1] : w2[0]) + r;
    }
}

// ---------------------------------------------------------------------------
// Skinny GEMM core v2: out[b][r] = sum_k inp[b][k] * W[r][k]
// 256 threads = 4 waves; wave owns a row-QUAD (4 rows), all 32 batches.
// Lane kt owns a float4 k-slice; acc[4][32] register tile (16 FMA per LDS
// read). x chunk double-buffered in LDS with XOR granule swizzle G^(G>>3)
// (conflict-free stage-writes AND b-loop reads). End: two 63-shuffle
// reduce-scatters; lane L holds (b=L&31, rr=L>>5); RoPE via shfl_xor(.,32).
// ---------------------------------------------------------------------------
__device__ __forceinline__ void gemm_core4(
    const float* __restrict__ inp, const float* __restrict__ W,
    float* __restrict__ outp, int stride, int row0, bool rope,
    const float* __restrict__ fc, const float* __restrict__ fs,
    float (*xs)[32][CHUNK], int kbeg, int nch, bool atomic)
{
    const int tid = threadIdx.x;         // 0..255
    const int wv  = tid >> 6;            // 0..3 wave = row-quad
    const int kt  = tid & 63;            // lane: k-slice
    const int rquad = row0 + wv * 4;

    const float* wp = W + (size_t)rquad * DIM + kbeg;

    // stage addressing: 256 threads x 32 floats = 32x256 chunk
    const int sb = tid >> 3;             // batch row 0..31
    const int sq = tid & 7;              // 32-float slot within row
    const float* sbase = inp + (size_t)sb * DIM + kbeg + sq * 32;
    const int pg = kt ^ (kt >> 3);       // swizzled read granule

    float acc[4][32];
#pragma unroll
    for (int r = 0; r < 4; ++r)
#pragma unroll
        for (int b = 0; b < 32; ++b) acc[r][b] = 0.f;

    float4 xr[8], wa[4], wb[4];
#pragma unroll
    for (int j = 0; j < 8; ++j) xr[j] = *(const float4*)(sbase + j * 4);
#pragma unroll
    for (int r = 0; r < 4; ++r) wa[r] = *(const float4*)(wp + (size_t)r * DIM + kt * 4);
#pragma unroll
    for (int j = 0; j < 8; ++j)
        *(float4*)(&xs[0][sb][(sq * 8 + (j ^ sq)) * 4]) = xr[j];

    int buf = 0;
    for (int ch = 0; ch < nch; ++ch) {
        __syncthreads();   // xs[buf] visible; prior reads of xs[buf^1] done
        const bool more = (ch + 1 < nch);
        if (more) {
            const int k1 = (ch + 1) * CHUNK;
#pragma unroll
            for (int j = 0; j < 8; ++j) xr[j] = *(const float4*)(sbase + k1 + j * 4);
#pragma unroll
            for (int r = 0; r < 4; ++r) wb[r] = *(const float4*)(wp + k1 + (size_t)r * DIM + kt * 4);
        }
        const float* xrow = &xs[buf][0][pg * 4];
#pragma unroll
        for (int b = 0; b < 32; ++b) {
            float4 xv = *(const float4*)(xrow + b * CHUNK);
#pragma unroll
            for (int r = 0; r < 4; ++r) {
                acc[r][b] = fmaf(wa[r].x, xv.x, acc[r][b]);
                acc[r][b] = fmaf(wa[r].y, xv.y, acc[r][b]);
                acc[r][b] = fmaf(wa[r].z, xv.z, acc[r][b]);
                acc[r][b] = fmaf(wa[r].w, xv.w, acc[r][b]);
            }
        }
        if (more) {
#pragma unroll
            for (int j = 0; j < 8; ++j)
                *(float4*)(&xs[buf ^ 1][sb][(sq * 8 + (j ^ sq)) * 4]) = xr[j];
#pragma unroll
            for (int r = 0; r < 4; ++r) wa[r] = wb[r];
        }
        buf ^= 1;
    }

    // reduce-scatter: set A = rows (rquad, rquad+1), set B = (rquad+2, rquad+3)
    float vv[64];
#pragma unroll
    for (int b = 0; b < 32; ++b) { vv[b] = acc[0][b]; vv[b + 32] = acc[1][b]; }
    float vA = rs64(vv);
#pragma unroll
    for (int b = 0; b < 32; ++b) { vv[b] = acc[2][b]; vv[b + 32] = acc[3][b]; }
    float vB = rs64(vv);

    const int bb = kt & 31, rr = kt >> 5;
    float pA = __shfl_xor(vA, 32);   // partner (other row of the pair)
    float pB = __shfl_xor(vB, 32);
    float outA, outB;
    if (rope) {
        const int iA = (rquad & (HD - 1)) >> 1;
        const int iB = ((rquad + 2) & (HD - 1)) >> 1;
        const float cA = fc[iA], sA = fs[iA], cB = fc[iB], sB = fs[iB];
        // rr==0 (even row): o0*c - o1*s ; rr==1 (odd row): o0*s + o1*c
        outA = rr ? fmaf(pA, sA, vA * cA) : fmaf(-pA, sA, vA * cA);
        outB = rr ? fmaf(pB, sB, vB * cB) : fmaf(-pB, sB, vB * cB);
    } else { outA = vA; outB = vB; }
    float* dstA = outp + (size_t)bb * stride + rquad + rr;
    if (atomic) {
        atomicAdd(dstA, outA);
        atomicAdd(dstA + 2, outB);
    } else {
        *dstA = outA;
        *(dstA + 2) = outB;
    }
}

// Fused Q/K/V projection + RoPE. Grid: 256 (q) + 64 (k) + 64 (v) = 384 blocks.
__global__ __launch_bounds__(256, 2) void qkv_gemm(
    const float* __restrict__ x,
    const float* __restrict__ wq, const float* __restrict__ wk, const float* __restrict__ wv,
    float* __restrict__ qo, float* __restrict__ ko, float* __restrict__ vo,
    const float* __restrict__ fc, const float* __restrict__ fs)
{
    __shared__ float xs[2][B][CHUNK];   // 64 KB
    int blk = blockIdx.x;
    const float* W; float* outp; int stride, row0; bool rope;
    if (blk < 256)      { W = wq; outp = qo; stride = NH * HD;  row0 = blk * 16;         rope = true;  }
    else if (blk < 320) { W = wk; outp = ko; stride = NKV * HD; row0 = (blk - 256) * 16; rope = true;  }
    else                { W = wv; outp = vo; stride = NKV * HD; row0 = (blk - 320) * 16; rope = false; }
    gemm_core4(x, W, outp, stride, row0, rope, fc, fs, xs, 0, DIM / CHUNK, false);
}

// Output projection, K-split x2: grid 512 blocks; block = (rowblk, khalf).
// Partial sums atomically accumulated into pre-zeroed d_out.
__global__ __launch_bounds__(256, 2) void gemm_wo_split(
    const float* __restrict__ inp, const float* __restrict__ W, float* __restrict__ outp)
{
    __shared__ float xs[2][B][CHUNK];   // 64 KB
    const int rowblk = blockIdx.x >> 1;
    const int kh     = blockIdx.x & 1;
    gemm_core4(inp, W, outp, DIM, rowblk * 16, false, nullptr, nullptr, xs,
               kh * (DIM / 2), (DIM / 2) / CHUNK, true);
}

__global__ __launch_bounds__(256) void zero_out_kernel(float4* __restrict__ p, int n4)
{
    int i = blockIdx.x * 256 + threadIdx.x;
    if (i < n4) p[i] = make_float4(0.f, 0.f, 0.f, 0.f);
}

// ---------------------------------------------------------------------------
// Split-flash decode attention (R2 form). Grid: B*NKV*SPLIT = 2048 blocks,
// 256 threads. Block (b,h,s) handles t in [s*256, s*256+256). t==2047 comes
// from the freshly projected k/v (inputs are not mutated).
// ---------------------------------------------------------------------------
__global__ __launch_bounds__(256) void attn_split_k(
    const float* __restrict__ qr, const float* __restrict__ kn, const float* __restrict__ vn,
    const float* __restrict__ ck, const float* __restrict__ cv,
    float* __restrict__ part_o, float* __restrict__ part_ml)
{
    __shared__ float q_lds[NREP][HD];       // 2 KB
    __shared__ float p_lds[TS][NREP];       // 4 KB
    __shared__ float red[4][NREP];          // wave partials
    __shared__ float o_scr[8][NREP][HD];    // 16 KB

    const int bid = blockIdx.x;
    const int s = bid & 7, h = (bid >> 3) & 7, b = bid >> 6;
    const int t0 = s * TS;
    const int tid = threadIdx.x;

    for (int i = tid; i < NREP * HD; i += 256)
        q_lds[i >> 7][i & 127] = qr[((size_t)b * NH + h * NREP + (i >> 7)) * HD + (i & 127)];
    __syncthreads();

    // ---- phase 1: scores, one thread per position t
    const int t = t0 + tid;
    const float* kptr = (t == TCACHE - 1)
        ? (kn + ((size_t)b * NKV + h) * HD)
        : (ck + (((size_t)b * TCACHE + t) * NKV + h) * HD);
    float s0 = 0.f, s1 = 0.f, s2 = 0.f, s3 = 0.f;
#pragma unroll 8
    for (int d = 0; d < HD; d += 4) {
        float4 kv = *(const float4*)(kptr + d);
        float4 q0 = *(const float4*)(&q_lds[0][d]);
        float4 q1 = *(const float4*)(&q_lds[1][d]);
        float4 q2 = *(const float4*)(&q_lds[2][d]);
        float4 q3 = *(const float4*)(&q_lds[3][d]);
        s0 = fmaf(q0.x, kv.x, s0); s0 = fmaf(q0.y, kv.y, s0); s0 = fmaf(q0.z, kv.z, s0); s0 = fmaf(q0.w, kv.w, s0);
        s1 = fmaf(q1.x, kv.x, s1); s1 = fmaf(q1.y, kv.y, s1); s1 = fmaf(q1.z, kv.z, s1); s1 = fmaf(q1.w, kv.w, s1);
        s2 = fmaf(q2.x, kv.x, s2); s2 = fmaf(q2.y, kv.y, s2); s2 = fmaf(q2.z, kv.z, s2); s2 = fmaf(q2.w, kv.w, s2);
        s3 = fmaf(q3.x, kv.x, s3); s3 = fmaf(q3.y, kv.y, s3); s3 = fmaf(q3.z, kv.z, s3); s3 = fmaf(q3.w, kv.w, s3);
    }
    const float scale = 0.088388347648318447f; // 1/sqrt(128)
    s0 *= scale; s1 *= scale; s2 *= scale; s3 *= scale;

    // ---- block softmax (split-local m, l)
    float m0 = s0, m1 = s1, m2 = s2, m3 = s3;
    for (int off = 1; off < 64; off <<= 1) {
        m0 = fmaxf(m0, __shfl_xor(m0, off));
        m1 = fmaxf(m1, __shfl_xor(m1, off));
        m2 = fmaxf(m2, __shfl_xor(m2, off));
        m3 = fmaxf(m3, __shfl_xor(m3, off));
    }
    const int wv_ = tid >> 6, lane = tid & 63;
    if (lane == 0) { red[wv_][0] = m0; red[wv_][1] = m1; red[wv_][2] = m2; red[wv_][3] = m3; }
    __syncthreads();
    m0 = fmaxf(fmaxf(red[0][0], red[1][0]), fmaxf(red[2][0], red[3][0]));
    m1 = fmaxf(fmaxf(red[0][1], red[1][1]), fmaxf(red[2][1], red[3][1]));
    m2 = fmaxf(fmaxf(red[0][2], red[1][2]), fmaxf(red[2][2], red[3][2]));
    m3 = fmaxf(fmaxf(red[0][3], red[1][3]), fmaxf(red[2][3], red[3][3]));
    float p0 = __expf(s0 - m0), p1 = __expf(s1 - m1), p2 = __expf(s2 - m2), p3 = __expf(s3 - m3);
    *(float4*)(&p_lds[tid][0]) = make_float4(p0, p1, p2, p3);
    float l0 = p0, l1 = p1, l2 = p2, l3 = p3;
    for (int off = 1; off < 64; off <<= 1) {
        l0 += __shfl_xor(l0, off);
        l1 += __shfl_xor(l1, off);
        l2 += __shfl_xor(l2, off);
        l3 += __shfl_xor(l3, off);
    }
    __syncthreads();   // all reads of red(max) + p_lds writes done
    if (lane == 0) { red[wv_][0] = l0; red[wv_][1] = l1; red[wv_][2] = l2; red[wv_][3] = l3; }
    __syncthreads();
    if (tid < NREP) {
        float l = red[0][tid] + red[1][tid] + red[2][tid] + red[3][tid];
        float m = (tid == 0) ? m0 : (tid == 1) ? m1 : (tid == 2) ? m2 : m3;
        part_ml[(size_t)bid * 8 + tid * 2]     = m;
        part_ml[(size_t)bid * 8 + tid * 2 + 1] = l;
    }

    // ---- phase 2: PV. 8 t-groups x 32 d-lanes, coalesced float4 V reads.
    const int g  = tid >> 5;
    const int dl = (tid & 31) << 2;
    float4 a0 = make_float4(0,0,0,0), a1 = a0, a2 = a0, a3 = a0;
    const int tb = t0 + g * 32;
#pragma unroll 4
    for (int j = 0; j < 32; ++j) {
        int tt = tb + j;
        const float* vptr = (tt == TCACHE - 1)
            ? (vn + ((size_t)b * NKV + h) * HD)
            : (cv + (((size_t)b * TCACHE + tt) * NKV + h) * HD);
        float4 vvv = *(const float4*)(vptr + dl);
        float4 pp  = *(const float4*)(&p_lds[g * 32 + j][0]);
        a0.x = fmaf(pp.x, vvv.x, a0.x); a0.y = fmaf(pp.x, vvv.y, a0.y); a0.z = fmaf(pp.x, vvv.z, a0.z); a0.w = fmaf(pp.x, vvv.w, a0.w);
        a1.x = fmaf(pp.y, vvv.x, a1.x); a1.y = fmaf(pp.y, vvv.y, a1.y); a1.z = fmaf(pp.y, vvv.z, a1.z); a1.w = fmaf(pp.y, vvv.w, a1.w);
        a2.x = fmaf(pp.z, vvv.x, a2.x); a2.y = fmaf(pp.z, vvv.y, a2.y); a2.z = fmaf(pp.z, vvv.z, a2.z); a2.w = fmaf(pp.z, vvv.w, a2.w);
        a3.x = fmaf(pp.w, vvv.x, a3.x); a3.y = fmaf(pp.w, vvv.y, a3.y); a3.z = fmaf(pp.w, vvv.z, a3.z); a3.w = fmaf(pp.w, vvv.w, a3.w);
    }
    *(float4*)(&o_scr[g][0][dl]) = a0;
    *(float4*)(&o_scr[g][1][dl]) = a1;
    *(float4*)(&o_scr[g][2][dl]) = a2;
    *(float4*)(&o_scr[g][3][dl]) = a3;
    __syncthreads();
    for (int oi = tid; oi < NREP * HD; oi += 256) {
        int r = oi >> 7, d = oi & 127;
        float sum = 0.f;
#pragma unroll
        for (int gg = 0; gg < 8; ++gg) sum += o_scr[gg][r][d];
        part_o[((size_t)bid * NREP + r) * HD + d] = sum;
    }
}

// Merge the SPLIT partials per (b,h). Grid: B*NKV = 256 blocks, 128 threads.
__global__ __launch_bounds__(128) void attn_combine(
    const float* __restrict__ part_o, const float* __restrict__ part_ml,
    float* __restrict__ attn_out)
{
    const int bh = blockIdx.x;          // b*NKV + h
    const int d  = threadIdx.x;         // 0..127
    const int b = bh >> 3, h = bh & 7;
#pragma unroll
    for (int r = 0; r < NREP; ++r) {
        float ms[SPLIT], ls[SPLIT];
        float M = -1e30f;
#pragma unroll
        for (int s = 0; s < SPLIT; ++s) {
            ms[s] = part_ml[(size_t)(bh * SPLIT + s) * 8 + r * 2];
            ls[s] = part_ml[(size_t)(bh * SPLIT + s) * 8 + r * 2 + 1];
            M = fmaxf(M, ms[s]);
        }
        float L = 0.f, o = 0.f;
#pragma unroll
        for (int s = 0; s < SPLIT; ++s) {
            float w = __expf(ms[s] - M);
            L += ls[s] * w;
            o = fmaf(w, part_o[((size_t)(bh * SPLIT + s) * NREP + r) * HD + d], o);
        }
        attn_out[((size_t)b * NH + (h * NREP + r)) * HD + d] = o / L;
    }
}

// ---------------------------------------------------------------------------
extern "C" void kernel_launch(void* const* d_in, const int* in_sizes, int n_in,
                              void* d_out, int out_size, void* d_ws, size_t ws_size,
                              hipStream_t stream)
{
    const float* x  = (const float*)d_in[0];
    const float* fc = (const float*)d_in[1];
    const float* fs = (const float*)d_in[2];
    const float* ck = (const float*)d_in[3];
    const float* cv = (const float*)d_in[4];
    const float* wq = (const float*)d_in[5];
    const float* wk = (const float*)d_in[6];
    const float* wv = (const float*)d_in[7];
    const float* wo = (const float*)d_in[8];
    // d_in[9] = start_pos (2047) — fixed by the problem shape, hardcoded.

    float* ws   = (float*)d_ws;
    float* q_r  = ws;                 // B*NH*HD      = 131072
    float* k_n  = ws + 131072;        // B*NKV*HD     = 32768
    float* v_n  = ws + 163840;        // B*NKV*HD     = 32768
    float* a_o  = ws + 196608;        // B*NH*HD      = 131072
    float* p_o  = ws + 327680;        // B*NKV*SPLIT*NREP*HD = 1048576
    float* p_ml = ws + 1376256;       // B*NKV*SPLIT*8       = 16384
    float* outp = (float*)d_out;

    zero_out_kernel<<<dim3((out_size / 4 + 255) / 256), dim3(256), 0, stream>>>(
        (float4*)outp, out_size / 4);
    qkv_gemm<<<dim3(384), dim3(256), 0, stream>>>(x, wq, wk, wv, q_r, k_n, v_n, fc, fs);
    attn_split_k<<<dim3(B * NKV * SPLIT), dim3(256), 0, stream>>>(q_r, k_n, v_n, ck, cv, p_o, p_ml);
    attn_combine<<<dim3(B * NKV), dim3(128), 0, stream>>>(p_o, p_ml, a_o);
    gemm_wo_split<<<dim3(512), dim3(256), 0, stream>>>(a_o, wo, outp);
}

// Round 5
// 211.221 us; speedup vs baseline: 1.6704x; 1.6704x over previous
//
#include <hip/hip_runtime.h>
#include <hip/hip_bf16.h>

#define B     32
#define DIM   4096
#define NH    32
#define NKV   8
#define HD    128
#define TCACHE 2048
#define NREP  4
#define SPLIT 8
#define TS    256   // positions per attention block
#define CHUNK 256   // k-chunk width for projection GEMMs

// ---------------------------------------------------------------------------
// Skinny GEMM core v3: out[b][r] = sum_k inp[b][k] * W[r][k]
// 512 threads = 8 waves = (4 row-groups) x (2 batch-halves).
// Wave owns 4 rows x 16 batches -> acc[4][16] = 64 VGPRs (no spill).
// Lane kt owns a float4 k-slice of each 256-wide chunk. Per chunk/thread:
// 16 ds_read_b128 feed 256 FMAs (LDS-issue wall ~= HBM wall, balanced).
// x chunk double-buffered in LDS; next chunk register-prefetched.
// Epilogue: full 64-lane butterfly per output (64 outputs = 64 lanes),
// RoPE pair completed via shfl_xor(.,16) (row r <-> r^1).
// ---------------------------------------------------------------------------
__device__ __forceinline__ void gemm_core_v3(
    const float* __restrict__ inp, const float* __restrict__ W,
    float* __restrict__ outp, int stride, int row0, bool rope,
    const float* __restrict__ fc, const float* __restrict__ fs,
    float (*xs)[B][CHUNK])
{
    const int tid = threadIdx.x;         // 0..511
    const int wid = tid >> 6;            // 0..7
    const int kt  = tid & 63;            // lane: k-slice
    const int rg  = wid >> 1;            // 0..3 row-group
    const int bh  = wid & 1;             // batch half
    const int r0  = row0 + rg * 4;       // first of this wave's 4 rows
    const int b0  = bh * 16;

    const float* wp = W + (size_t)r0 * DIM;

    // staging: thread covers batch sb = tid>>4, 16 floats at col (tid&15)*16
    const int sb = tid >> 4;
    const int sc = (tid & 15) * 16;
    const float* sbase = inp + (size_t)sb * DIM + sc;

    float acc[4][16];
#pragma unroll
    for (int r = 0; r < 4; ++r)
#pragma unroll
        for (int b = 0; b < 16; ++b) acc[r][b] = 0.f;

    float4 xr[4], wa[4];
#pragma unroll
    for (int j = 0; j < 4; ++j) xr[j] = *(const float4*)(sbase + j * 4);
#pragma unroll
    for (int r = 0; r < 4; ++r) wa[r] = *(const float4*)(wp + (size_t)r * DIM + kt * 4);
#pragma unroll
    for (int j = 0; j < 4; ++j)
        *(float4*)(&xs[0][sb][sc + j * 4]) = xr[j];

    int buf = 0;
    for (int ch = 0; ch < DIM / CHUNK; ++ch) {
        __syncthreads();   // xs[buf] writes visible; prior reads of xs[buf^1] done
        const bool more = (ch + 1 < DIM / CHUNK);
        float4 wb[4];
        if (more) {
            const int k1 = (ch + 1) * CHUNK;
#pragma unroll
            for (int j = 0; j < 4; ++j) xr[j] = *(const float4*)(sbase + k1 + j * 4);
#pragma unroll
            for (int r = 0; r < 4; ++r) wb[r] = *(const float4*)(wp + k1 + (size_t)r * DIM + kt * 4);
        }
        const float* xrow = &xs[buf][b0][kt * 4];
#pragma unroll
        for (int b = 0; b < 16; ++b) {
            float4 xv = *(const float4*)(xrow + b * CHUNK);
#pragma unroll
            for (int r = 0; r < 4; ++r) {
                acc[r][b] = fmaf(wa[r].x, xv.x, acc[r][b]);
                acc[r][b] = fmaf(wa[r].y, xv.y, acc[r][b]);
                acc[r][b] = fmaf(wa[r].z, xv.z, acc[r][b]);
                acc[r][b] = fmaf(wa[r].w, xv.w, acc[r][b]);
            }
        }
        if (more) {
#pragma unroll
            for (int j = 0; j < 4; ++j)
                *(float4*)(&xs[buf ^ 1][sb][sc + j * 4]) = xr[j];
#pragma unroll
            for (int r = 0; r < 4; ++r) wa[r] = wb[r];
        }
        buf ^= 1;
    }

    // epilogue: 64 outputs (r in 0..3, bb in 0..15); target lane = r*16+bb
    float myout = 0.f;
#pragma unroll
    for (int r = 0; r < 4; ++r) {
#pragma unroll
        for (int bb = 0; bb < 16; ++bb) {
            float v = acc[r][bb];
#pragma unroll
            for (int off = 1; off < 64; off <<= 1) v += __shfl_xor(v, off);
            if (kt == r * 16 + bb) myout = v;
        }
    }

    const int orow = kt >> 4;            // my row within quad
    const int ob   = b0 + (kt & 15);     // my batch
    float res;
    if (rope) {
        const float prt = __shfl_xor(myout, 16);   // partner row r^1, same batch
        const int gr = r0 + orow;
        const int fi = (gr & (HD - 1)) >> 1;
        const float c = fc[fi], s = fs[fi];
        // even row: v*c - partner*s ; odd row: partner*s + v*c
        res = (gr & 1) ? fmaf(myout, c, prt * s) : fmaf(myout, c, -prt * s);
    } else {
        res = myout;
    }
    outp[(size_t)ob * stride + r0 + orow] = res;
}

// Fused Q/K/V projection + RoPE. Grid: 256 (q) + 64 (k) + 64 (v) = 384 blocks.
__global__ __launch_bounds__(512, 2) void qkv_gemm(
    const float* __restrict__ x,
    const float* __restrict__ wq, const float* __restrict__ wk, const float* __restrict__ wv,
    float* __restrict__ qo, float* __restrict__ ko, float* __restrict__ vo,
    const float* __restrict__ fc, const float* __restrict__ fs)
{
    __shared__ float xs[2][B][CHUNK];   // 64 KB
    int blk = blockIdx.x;
    const float* W; float* outp; int stride, row0; bool rope;
    if (blk < 256)      { W = wq; outp = qo; stride = NH * HD;  row0 = blk * 16;         rope = true;  }
    else if (blk < 320) { W = wk; outp = ko; stride = NKV * HD; row0 = (blk - 256) * 16; rope = true;  }
    else                { W = wv; outp = vo; stride = NKV * HD; row0 = (blk - 320) * 16; rope = false; }
    gemm_core_v3(x, W, outp, stride, row0, rope, fc, fs, xs);
}

// Output projection: d_out[b][d] = sum_e attn[b][e] * wo[d][e]. Grid: 256.
__global__ __launch_bounds__(512, 2) void gemm_wo(
    const float* __restrict__ inp, const float* __restrict__ W, float* __restrict__ outp)
{
    __shared__ float xs[2][B][CHUNK];   // 64 KB
    gemm_core_v3(inp, W, outp, DIM, blockIdx.x * 16, false, nullptr, nullptr, xs);
}

// ---------------------------------------------------------------------------
// Split-flash decode attention (R2 form, proven). Grid: B*NKV*SPLIT = 2048
// blocks, 256 threads. Block (b,h,s) handles t in [s*256, s*256+256).
// t==2047 comes from the freshly projected k/v (inputs are not mutated).
// ---------------------------------------------------------------------------
__global__ __launch_bounds__(256) void attn_split_k(
    const float* __restrict__ qr, const float* __restrict__ kn, const float* __restrict__ vn,
    const float* __restrict__ ck, const float* __restrict__ cv,
    float* __restrict__ part_o, float* __restrict__ part_ml)
{
    __shared__ float q_lds[NREP][HD];       // 2 KB
    __shared__ float p_lds[TS][NREP];       // 4 KB
    __shared__ float red[4][NREP];          // wave partials
    __shared__ float o_scr[8][NREP][HD];    // 16 KB

    const int bid = blockIdx.x;
    const int s = bid & 7, h = (bid >> 3) & 7, b = bid >> 6;
    const int t0 = s * TS;
    const int tid = threadIdx.x;

    for (int i = tid; i < NREP * HD; i += 256)
        q_lds[i >> 7][i & 127] = qr[((size_t)b * NH + h * NREP + (i >> 7)) * HD + (i & 127)];
    __syncthreads();

    // ---- phase 1: scores, one thread per position t
    const int t = t0 + tid;
    const float* kptr = (t == TCACHE - 1)
        ? (kn + ((size_t)b * NKV + h) * HD)
        : (ck + (((size_t)b * TCACHE + t) * NKV + h) * HD);
    float s0 = 0.f, s1 = 0.f, s2 = 0.f, s3 = 0.f;
#pragma unroll 8
    for (int d = 0; d < HD; d += 4) {
        float4 kv = *(const float4*)(kptr + d);
        float4 q0 = *(const float4*)(&q_lds[0][d]);
        float4 q1 = *(const float4*)(&q_lds[1][d]);
        float4 q2 = *(const float4*)(&q_lds[2][d]);
        float4 q3 = *(const float4*)(&q_lds[3][d]);
        s0 = fmaf(q0.x, kv.x, s0); s0 = fmaf(q0.y, kv.y, s0); s0 = fmaf(q0.z, kv.z, s0); s0 = fmaf(q0.w, kv.w, s0);
        s1 = fmaf(q1.x, kv.x, s1); s1 = fmaf(q1.y, kv.y, s1); s1 = fmaf(q1.z, kv.z, s1); s1 = fmaf(q1.w, kv.w, s1);
        s2 = fmaf(q2.x, kv.x, s2); s2 = fmaf(q2.y, kv.y, s2); s2 = fmaf(q2.z, kv.z, s2); s2 = fmaf(q2.w, kv.w, s2);
        s3 = fmaf(q3.x, kv.x, s3); s3 = fmaf(q3.y, kv.y, s3); s3 = fmaf(q3.z, kv.z, s3); s3 = fmaf(q3.w, kv.w, s3);
    }
    const float scale = 0.088388347648318447f; // 1/sqrt(128)
    s0 *= scale; s1 *= scale; s2 *= scale; s3 *= scale;

    // ---- block softmax (split-local m, l)
    float m0 = s0, m1 = s1, m2 = s2, m3 = s3;
    for (int off = 1; off < 64; off <<= 1) {
        m0 = fmaxf(m0, __shfl_xor(m0, off));
        m1 = fmaxf(m1, __shfl_xor(m1, off));
        m2 = fmaxf(m2, __shfl_xor(m2, off));
        m3 = fmaxf(m3, __shfl_xor(m3, off));
    }
    const int wv_ = tid >> 6, lane = tid & 63;
    if (lane == 0) { red[wv_][0] = m0; red[wv_][1] = m1; red[wv_][2] = m2; red[wv_][3] = m3; }
    __syncthreads();
    m0 = fmaxf(fmaxf(red[0][0], red[1][0]), fmaxf(red[2][0], red[3][0]));
    m1 = fmaxf(fmaxf(red[0][1], red[1][1]), fmaxf(red[2][1], red[3][1]));
    m2 = fmaxf(fmaxf(red[0][2], red[1][2]), fmaxf(red[2][2], red[3][2]));
    m3 = fmaxf(fmaxf(red[0][3], red[1][3]), fmaxf(red[2][3], red[3][3]));
    float p0 = __expf(s0 - m0), p1 = __expf(s1 - m1), p2 = __expf(s2 - m2), p3 = __expf(s3 - m3);
    *(float4*)(&p_lds[tid][0]) = make_float4(p0, p1, p2, p3);
    float l0 = p0, l1 = p1, l2 = p2, l3 = p3;
    for (int off = 1; off < 64; off <<= 1) {
        l0 += __shfl_xor(l0, off);
        l1 += __shfl_xor(l1, off);
        l2 += __shfl_xor(l2, off);
        l3 += __shfl_xor(l3, off);
    }
    __syncthreads();   // all reads of red(max) + p_lds writes done
    if (lane == 0) { red[wv_][0] = l0; red[wv_][1] = l1; red[wv_][2] = l2; red[wv_][3] = l3; }
    __syncthreads();
    if (tid < NREP) {
        float l = red[0][tid] + red[1][tid] + red[2][tid] + red[3][tid];
        float m = (tid == 0) ? m0 : (tid == 1) ? m1 : (tid == 2) ? m2 : m3;
        part_ml[(size_t)bid * 8 + tid * 2]     = m;
        part_ml[(size_t)bid * 8 + tid * 2 + 1] = l;
    }

    // ---- phase 2: PV. 8 t-groups x 32 d-lanes, coalesced float4 V reads.
    const int g  = tid >> 5;
    const int dl = (tid & 31) << 2;
    float4 a0 = make_float4(0,0,0,0), a1 = a0, a2 = a0, a3 = a0;
    const int tb = t0 + g * 32;
#pragma unroll 4
    for (int j = 0; j < 32; ++j) {
        int tt = tb + j;
        const float* vptr = (tt == TCACHE - 1)
            ? (vn + ((size_t)b * NKV + h) * HD)
            : (cv + (((size_t)b * TCACHE + tt) * NKV + h) * HD);
        float4 vvv = *(const float4*)(vptr + dl);
        float4 pp  = *(const float4*)(&p_lds[g * 32 + j][0]);
        a0.x = fmaf(pp.x, vvv.x, a0.x); a0.y = fmaf(pp.x, vvv.y, a0.y); a0.z = fmaf(pp.x, vvv.z, a0.z); a0.w = fmaf(pp.x, vvv.w, a0.w);
        a1.x = fmaf(pp.y, vvv.x, a1.x); a1.y = fmaf(pp.y, vvv.y, a1.y); a1.z = fmaf(pp.y, vvv.z, a1.z); a1.w = fmaf(pp.y, vvv.w, a1.w);
        a2.x = fmaf(pp.z, vvv.x, a2.x); a2.y = fmaf(pp.z, vvv.y, a2.y); a2.z = fmaf(pp.z, vvv.z, a2.z); a2.w = fmaf(pp.z, vvv.w, a2.w);
        a3.x = fmaf(pp.w, vvv.x, a3.x); a3.y = fmaf(pp.w, vvv.y, a3.y); a3.z = fmaf(pp.w, vvv.z, a3.z); a3.w = fmaf(pp.w, vvv.w, a3.w);
    }
    *(float4*)(&o_scr[g][0][dl]) = a0;
    *(float4*)(&o_scr[g][1][dl]) = a1;
    *(float4*)(&o_scr[g][2][dl]) = a2;
    *(float4*)(&o_scr[g][3][dl]) = a3;
    __syncthreads();
    for (int oi = tid; oi < NREP * HD; oi += 256) {
        int r = oi >> 7, d = oi & 127;
        float sum = 0.f;
#pragma unroll
        for (int gg = 0; gg < 8; ++gg) sum += o_scr[gg][r][d];
        part_o[((size_t)bid * NREP + r) * HD + d] = sum;
    }
}

// Merge the SPLIT partials per (b,h). Grid: B*NKV = 256 blocks, 128 threads.
__global__ __launch_bounds__(128) void attn_combine(
    const float* __restrict__ part_o, const float* __restrict__ part_ml,
    float* __restrict__ attn_out)
{
    const int bh = blockIdx.x;          // b*NKV + h
    const int d  = threadIdx.x;         // 0..127
    const int b = bh >> 3, h = bh & 7;
#pragma unroll
    for (int r = 0; r < NREP; ++r) {
        float ms[SPLIT], ls[SPLIT];
        float M = -1e30f;
#pragma unroll
        for (int s = 0; s < SPLIT; ++s) {
            ms[s] = part_ml[(size_t)(bh * SPLIT + s) * 8 + r * 2];
            ls[s] = part_ml[(size_t)(bh * SPLIT + s) * 8 + r * 2 + 1];
            M = fmaxf(M, ms[s]);
        }
        float L = 0.f, o = 0.f;
#pragma unroll
        for (int s = 0; s < SPLIT; ++s) {
            float w = __expf(ms[s] - M);
            L += ls[s] * w;
            o = fmaf(w, part_o[((size_t)(bh * SPLIT + s) * NREP + r) * HD + d], o);
        }
        attn_out[((size_t)b * NH + (h * NREP + r)) * HD + d] = o / L;
    }
}

// ---------------------------------------------------------------------------
extern "C" void kernel_launch(void* const* d_in, const int* in_sizes, int n_in,
                              void* d_out, int out_size, void* d_ws, size_t ws_size,
                              hipStream_t stream)
{
    const float* x  = (const float*)d_in[0];
    const float* fc = (const float*)d_in[1];
    const float* fs = (const float*)d_in[2];
    const float* ck = (const float*)d_in[3];
    const float* cv = (const float*)d_in[4];
    const float* wq = (const float*)d_in[5];
    const float* wk = (const float*)d_in[6];
    const float* wv = (const float*)d_in[7];
    const float* wo = (const float*)d_in[8];
    // d_in[9] = start_pos (2047) — fixed by the problem shape, hardcoded.

    float* ws   = (float*)d_ws;
    float* q_r  = ws;                 // B*NH*HD      = 131072
    float* k_n  = ws + 131072;        // B*NKV*HD     = 32768
    float* v_n  = ws + 163840;        // B*NKV*HD     = 32768
    float* a_o  = ws + 196608;        // B*NH*HD      = 131072
    float* p_o  = ws + 327680;        // B*NKV*SPLIT*NREP*HD = 1048576
    float* p_ml = ws + 1376256;       // B*NKV*SPLIT*8       = 16384
    float* outp = (float*)d_out;

    qkv_gemm<<<dim3(384), dim3(512), 0, stream>>>(x, wq, wk, wv, q_r, k_n, v_n, fc, fs);
    attn_split_k<<<dim3(B * NKV * SPLIT), dim3(256), 0, stream>>>(q_r, k_n, v_n, ck, cv, p_o, p_ml);
    attn_combine<<<dim3(B * NKV), dim3(128), 0, stream>>>(p_o, p_ml, a_o);
    gemm_wo<<<dim3(256), dim3(512), 0, stream>>>(a_o, wo, outp);
}

// Round 6
// 209.197 us; speedup vs baseline: 1.6866x; 1.0097x over previous
//
#include <hip/hip_runtime.h>
#include <hip/hip_bf16.h>

#define B     32
#define DIM   4096
#define NH    32
#define NKV   8
#define HD    128
#define TCACHE 2048
#define NREP  4
#define SPLIT 8
#define TS    256   // positions per attention block
#define CHUNK 256   // k-chunk width for projection GEMMs

// ---------------------------------------------------------------------------
// Skinny GEMM core v3 (proven R5): out[b][r] = sum_k inp[b][k] * W[r][k]
// 512 threads = 8 waves = (4 row-groups) x (2 batch-halves); acc[4][16].
// ---------------------------------------------------------------------------
__device__ __forceinline__ void gemm_core_v3(
    const float* __restrict__ inp, const float* __restrict__ W,
    float* __restrict__ outp, int stride, int row0, bool rope,
    const float* __restrict__ fc, const float* __restrict__ fs,
    float (*xs)[B][CHUNK])
{
    const int tid = threadIdx.x;         // 0..511
    const int wid = tid >> 6;            // 0..7
    const int kt  = tid & 63;            // lane: k-slice
    const int rg  = wid >> 1;            // 0..3 row-group
    const int bh  = wid & 1;             // batch half
    const int r0  = row0 + rg * 4;       // first of this wave's 4 rows
    const int b0  = bh * 16;

    const float* wp = W + (size_t)r0 * DIM;

    const int sb = tid >> 4;
    const int sc = (tid & 15) * 16;
    const float* sbase = inp + (size_t)sb * DIM + sc;

    float acc[4][16];
#pragma unroll
    for (int r = 0; r < 4; ++r)
#pragma unroll
        for (int b = 0; b < 16; ++b) acc[r][b] = 0.f;

    float4 xr[4], wa[4];
#pragma unroll
    for (int j = 0; j < 4; ++j) xr[j] = *(const float4*)(sbase + j * 4);
#pragma unroll
    for (int r = 0; r < 4; ++r) wa[r] = *(const float4*)(wp + (size_t)r * DIM + kt * 4);
#pragma unroll
    for (int j = 0; j < 4; ++j)
        *(float4*)(&xs[0][sb][sc + j * 4]) = xr[j];

    int buf = 0;
    for (int ch = 0; ch < DIM / CHUNK; ++ch) {
        __syncthreads();
        const bool more = (ch + 1 < DIM / CHUNK);
        float4 wb[4];
        if (more) {
            const int k1 = (ch + 1) * CHUNK;
#pragma unroll
            for (int j = 0; j < 4; ++j) xr[j] = *(const float4*)(sbase + k1 + j * 4);
#pragma unroll
            for (int r = 0; r < 4; ++r) wb[r] = *(const float4*)(wp + k1 + (size_t)r * DIM + kt * 4);
        }
        const float* xrow = &xs[buf][b0][kt * 4];
#pragma unroll
        for (int b = 0; b < 16; ++b) {
            float4 xv = *(const float4*)(xrow + b * CHUNK);
#pragma unroll
            for (int r = 0; r < 4; ++r) {
                acc[r][b] = fmaf(wa[r].x, xv.x, acc[r][b]);
                acc[r][b] = fmaf(wa[r].y, xv.y, acc[r][b]);
                acc[r][b] = fmaf(wa[r].z, xv.z, acc[r][b]);
                acc[r][b] = fmaf(wa[r].w, xv.w, acc[r][b]);
            }
        }
        if (more) {
#pragma unroll
            for (int j = 0; j < 4; ++j)
                *(float4*)(&xs[buf ^ 1][sb][sc + j * 4]) = xr[j];
#pragma unroll
            for (int r = 0; r < 4; ++r) wa[r] = wb[r];
        }
        buf ^= 1;
    }

    float myout = 0.f;
#pragma unroll
    for (int r = 0; r < 4; ++r) {
#pragma unroll
        for (int bb = 0; bb < 16; ++bb) {
            float v = acc[r][bb];
#pragma unroll
            for (int off = 1; off < 64; off <<= 1) v += __shfl_xor(v, off);
            if (kt == r * 16 + bb) myout = v;
        }
    }

    const int orow = kt >> 4;
    const int ob   = b0 + (kt & 15);
    float res;
    if (rope) {
        const float prt = __shfl_xor(myout, 16);
        const int gr = r0 + orow;
        const int fi = (gr & (HD - 1)) >> 1;
        const float c = fc[fi], s = fs[fi];
        res = (gr & 1) ? fmaf(myout, c, prt * s) : fmaf(myout, c, -prt * s);
    } else {
        res = myout;
    }
    outp[(size_t)ob * stride + r0 + orow] = res;
}

__global__ __launch_bounds__(512, 2) void qkv_gemm(
    const float* __restrict__ x,
    const float* __restrict__ wq, const float* __restrict__ wk, const float* __restrict__ wv,
    float* __restrict__ qo, float* __restrict__ ko, float* __restrict__ vo,
    const float* __restrict__ fc, const float* __restrict__ fs)
{
    __shared__ float xs[2][B][CHUNK];   // 64 KB
    int blk = blockIdx.x;
    const float* W; float* outp; int stride, row0; bool rope;
    if (blk < 256)      { W = wq; outp = qo; stride = NH * HD;  row0 = blk * 16;         rope = true;  }
    else if (blk < 320) { W = wk; outp = ko; stride = NKV * HD; row0 = (blk - 256) * 16; rope = true;  }
    else                { W = wv; outp = vo; stride = NKV * HD; row0 = (blk - 320) * 16; rope = false; }
    gemm_core_v3(x, W, outp, stride, row0, rope, fc, fs, xs);
}

__global__ __launch_bounds__(512, 2) void gemm_wo(
    const float* __restrict__ inp, const float* __restrict__ W, float* __restrict__ outp)
{
    __shared__ float xs[2][B][CHUNK];   // 64 KB
    gemm_core_v3(inp, W, outp, DIM, blockIdx.x * 16, false, nullptr, nullptr, xs);
}

// ---------------------------------------------------------------------------
// Split-flash decode attention v2. Grid: B*NKV*SPLIT = 2048 blocks, 256 thr.
// Block (b,h,s) handles t in [s*256, s*256+256). t==2047 from fresh k/v.
// Phase 1: 16-lane cooperative rows — coalesced 256B segments (4 pages/inst
// instead of 64), 4-step butterfly reduce, scores through s_lds.
// ---------------------------------------------------------------------------
__global__ __launch_bounds__(256) void attn_split_k(
    const float* __restrict__ qr, const float* __restrict__ kn, const float* __restrict__ vn,
    const float* __restrict__ ck, const float* __restrict__ cv,
    float* __restrict__ part_o, float* __restrict__ part_ml)
{
    __shared__ float q_lds[NREP][HD];       // 2 KB
    __shared__ float s_lds[TS][NREP];       // 4 KB
    __shared__ float p_lds[TS][NREP];       // 4 KB
    __shared__ float red[4][NREP];          // wave partials
    __shared__ float o_scr[8][NREP][HD];    // 16 KB

    const int bid = blockIdx.x;
    const int s = bid & 7, h = (bid >> 3) & 7, b = bid >> 6;
    const int t0 = s * TS;
    const int tid = threadIdx.x;

    for (int i = tid; i < NREP * HD; i += 256)
        q_lds[i >> 7][i & 127] = qr[((size_t)b * NH + h * NREP + (i >> 7)) * HD + (i & 127)];
    __syncthreads();

    // ---- phase 1: scores, 16-lane cooperative rows
    const int l16 = tid & 15;
    const int sub = (tid >> 4) & 3;
    const int w   = tid >> 6;
    const int dA  = l16 * 4;
    const int dB  = 64 + l16 * 4;

    float4 qA[NREP], qB[NREP];
#pragma unroll
    for (int hh = 0; hh < NREP; ++hh) {
        qA[hh] = *(const float4*)(&q_lds[hh][dA]);
        qB[hh] = *(const float4*)(&q_lds[hh][dB]);
    }

    const float* kbase = ck + (((size_t)b * TCACHE + t0) * NKV + h) * HD;  // stride NKV*HD
    const float* knew  = kn + ((size_t)b * NKV + h) * HD;

#pragma unroll 4
    for (int i = 0; i < 16; ++i) {
        const int rl = w * 64 + i * 4 + sub;     // local row 0..255
        const float* kp = (t0 + rl == TCACHE - 1) ? knew
                          : (kbase + (size_t)rl * (NKV * HD));
        float4 kA = *(const float4*)(kp + dA);
        float4 kB = *(const float4*)(kp + dB);
        float e0, e1, e2, e3;
        e0 = qA[0].x * kA.x; e1 = qA[1].x * kA.x; e2 = qA[2].x * kA.x; e3 = qA[3].x * kA.x;
        e0 = fmaf(qA[0].y, kA.y, e0); e1 = fmaf(qA[1].y, kA.y, e1); e2 = fmaf(qA[2].y, kA.y, e2); e3 = fmaf(qA[3].y, kA.y, e3);
        e0 = fmaf(qA[0].z, kA.z, e0); e1 = fmaf(qA[1].z, kA.z, e1); e2 = fmaf(qA[2].z, kA.z, e2); e3 = fmaf(qA[3].z, kA.z, e3);
        e0 = fmaf(qA[0].w, kA.w, e0); e1 = fmaf(qA[1].w, kA.w, e1); e2 = fmaf(qA[2].w, kA.w, e2); e3 = fmaf(qA[3].w, kA.w, e3);
        e0 = fmaf(qB[0].x, kB.x, e0); e1 = fmaf(qB[1].x, kB.x, e1); e2 = fmaf(qB[2].x, kB.x, e2); e3 = fmaf(qB[3].x, kB.x, e3);
        e0 = fmaf(qB[0].y, kB.y, e0); e1 = fmaf(qB[1].y, kB.y, e1); e2 = fmaf(qB[2].y, kB.y, e2); e3 = fmaf(qB[3].y, kB.y, e3);
        e0 = fmaf(qB[0].z, kB.z, e0); e1 = fmaf(qB[1].z, kB.z, e1); e2 = fmaf(qB[2].z, kB.z, e2); e3 = fmaf(qB[3].z, kB.z, e3);
        e0 = fmaf(qB[0].w, kB.w, e0); e1 = fmaf(qB[1].w, kB.w, e1); e2 = fmaf(qB[2].w, kB.w, e2); e3 = fmaf(qB[3].w, kB.w, e3);
#pragma unroll
        for (int off = 1; off < 16; off <<= 1) {
            e0 += __shfl_xor(e0, off);
            e1 += __shfl_xor(e1, off);
            e2 += __shfl_xor(e2, off);
            e3 += __shfl_xor(e3, off);
        }
        if (l16 < NREP) {
            float sc = (l16 == 0) ? e0 : (l16 == 1) ? e1 : (l16 == 2) ? e2 : e3;
            s_lds[rl][l16] = sc;
        }
    }
    __syncthreads();

    // ---- block softmax (split-local m, l); thread tid owns row t0+tid
    float4 sv = *(const float4*)(&s_lds[tid][0]);
    const float scale = 0.088388347648318447f; // 1/sqrt(128)
    float s0 = sv.x * scale, s1 = sv.y * scale, s2 = sv.z * scale, s3 = sv.w * scale;

    float m0 = s0, m1 = s1, m2 = s2, m3 = s3;
    for (int off = 1; off < 64; off <<= 1) {
        m0 = fmaxf(m0, __shfl_xor(m0, off));
        m1 = fmaxf(m1, __shfl_xor(m1, off));
        m2 = fmaxf(m2, __shfl_xor(m2, off));
        m3 = fmaxf(m3, __shfl_xor(m3, off));
    }
    const int wv_ = tid >> 6, lane = tid & 63;
    if (lane == 0) { red[wv_][0] = m0; red[wv_][1] = m1; red[wv_][2] = m2; red[wv_][3] = m3; }
    __syncthreads();
    m0 = fmaxf(fmaxf(red[0][0], red[1][0]), fmaxf(red[2][0], red[3][0]));
    m1 = fmaxf(fmaxf(red[0][1], red[1][1]), fmaxf(red[2][1], red[3][1]));
    m2 = fmaxf(fmaxf(red[0][2], red[1][2]), fmaxf(red[2][2], red[3][2]));
    m3 = fmaxf(fmaxf(red[0][3], red[1][3]), fmaxf(red[2][3], red[3][3]));
    float p0 = __expf(s0 - m0), p1 = __expf(s1 - m1), p2 = __expf(s2 - m2), p3 = __expf(s3 - m3);
    *(float4*)(&p_lds[tid][0]) = make_float4(p0, p1, p2, p3);
    float l0 = p0, l1 = p1, l2 = p2, l3 = p3;
    for (int off = 1; off < 64; off <<= 1) {
        l0 += __shfl_xor(l0, off);
        l1 += __shfl_xor(l1, off);
        l2 += __shfl_xor(l2, off);
        l3 += __shfl_xor(l3, off);
    }
    __syncthreads();
    if (lane == 0) { red[wv_][0] = l0; red[wv_][1] = l1; red[wv_][2] = l2; red[wv_][3] = l3; }
    __syncthreads();
    if (tid < NREP) {
        float l = red[0][tid] + red[1][tid] + red[2][tid] + red[3][tid];
        float m = (tid == 0) ? m0 : (tid == 1) ? m1 : (tid == 2) ? m2 : m3;
        part_ml[(size_t)bid * 8 + tid * 2]     = m;
        part_ml[(size_t)bid * 8 + tid * 2 + 1] = l;
    }

    // ---- phase 2: PV. 8 t-groups x 32 d-lanes, coalesced float4 V reads.
    const int g  = tid >> 5;
    const int dl = (tid & 31) << 2;
    float4 a0 = make_float4(0,0,0,0), a1 = a0, a2 = a0, a3 = a0;
    const int tb = t0 + g * 32;
#pragma unroll 4
    for (int j = 0; j < 32; ++j) {
        int tt = tb + j;
        const float* vptr = (tt == TCACHE - 1)
            ? (vn + ((size_t)b * NKV + h) * HD)
            : (cv + (((size_t)b * TCACHE + tt) * NKV + h) * HD);
        float4 vvv = *(const float4*)(vptr + dl);
        float4 pp  = *(const float4*)(&p_lds[g * 32 + j][0]);
        a0.x = fmaf(pp.x, vvv.x, a0.x); a0.y = fmaf(pp.x, vvv.y, a0.y); a0.z = fmaf(pp.x, vvv.z, a0.z); a0.w = fmaf(pp.x, vvv.w, a0.w);
        a1.x = fmaf(pp.y, vvv.x, a1.x); a1.y = fmaf(pp.y, vvv.y, a1.y); a1.z = fmaf(pp.y, vvv.z, a1.z); a1.w = fmaf(pp.y, vvv.w, a1.w);
        a2.x = fmaf(pp.z, vvv.x, a2.x); a2.y = fmaf(pp.z, vvv.y, a2.y); a2.z = fmaf(pp.z, vvv.z, a2.z); a2.w = fmaf(pp.z, vvv.w, a2.w);
        a3.x = fmaf(pp.w, vvv.x, a3.x); a3.y = fmaf(pp.w, vvv.y, a3.y); a3.z = fmaf(pp.w, vvv.z, a3.z); a3.w = fmaf(pp.w, vvv.w, a3.w);
    }
    *(float4*)(&o_scr[g][0][dl]) = a0;
    *(float4*)(&o_scr[g][1][dl]) = a1;
    *(float4*)(&o_scr[g][2][dl]) = a2;
    *(float4*)(&o_scr[g][3][dl]) = a3;
    __syncthreads();
    for (int oi = tid; oi < NREP * HD; oi += 256) {
        int r = oi >> 7, d = oi & 127;
        float sum = 0.f;
#pragma unroll
        for (int gg = 0; gg < 8; ++gg) sum += o_scr[gg][r][d];
        part_o[((size_t)bid * NREP + r) * HD + d] = sum;
    }
}

// Merge the SPLIT partials per (b,h). Grid: B*NKV = 256 blocks, 128 threads.
__global__ __launch_bounds__(128) void attn_combine(
    const float* __restrict__ part_o, const float* __restrict__ part_ml,
    float* __restrict__ attn_out)
{
    const int bh = blockIdx.x;          // b*NKV + h
    const int d  = threadIdx.x;         // 0..127
    const int b = bh >> 3, h = bh & 7;
#pragma unroll
    for (int r = 0; r < NREP; ++r) {
        float ms[SPLIT], ls[SPLIT];
        float M = -1e30f;
#pragma unroll
        for (int s = 0; s < SPLIT; ++s) {
            ms[s] = part_ml[(size_t)(bh * SPLIT + s) * 8 + r * 2];
            ls[s] = part_ml[(size_t)(bh * SPLIT + s) * 8 + r * 2 + 1];
            M = fmaxf(M, ms[s]);
        }
        float L = 0.f, o = 0.f;
#pragma unroll
        for (int s = 0; s < SPLIT; ++s) {
            float w = __expf(ms[s] - M);
            L += ls[s] * w;
            o = fmaf(w, part_o[((size_t)(bh * SPLIT + s) * NREP + r) * HD + d], o);
        }
        attn_out[((size_t)b * NH + (h * NREP + r)) * HD + d] = o / L;
    }
}

// ---------------------------------------------------------------------------
extern "C" void kernel_launch(void* const* d_in, const int* in_sizes, int n_in,
                              void* d_out, int out_size, void* d_ws, size_t ws_size,
                              hipStream_t stream)
{
    const float* x  = (const float*)d_in[0];
    const float* fc = (const float*)d_in[1];
    const float* fs = (const float*)d_in[2];
    const float* ck = (const float*)d_in[3];
    const float* cv = (const float*)d_in[4];
    const float* wq = (const float*)d_in[5];
    const float* wk = (const float*)d_in[6];
    const float* wv = (const float*)d_in[7];
    const float* wo = (const float*)d_in[8];
    // d_in[9] = start_pos (2047) — fixed by the problem shape, hardcoded.

    float* ws   = (float*)d_ws;
    float* q_r  = ws;                 // B*NH*HD      = 131072
    float* k_n  = ws + 131072;        // B*NKV*HD     = 32768
    float* v_n  = ws + 163840;        // B*NKV*HD     = 32768
    float* a_o  = ws + 196608;        // B*NH*HD      = 131072
    float* p_o  = ws + 327680;        // B*NKV*SPLIT*NREP*HD = 1048576
    float* p_ml = ws + 1376256;       // B*NKV*SPLIT*8       = 16384
    float* outp = (float*)d_out;

    qkv_gemm<<<dim3(384), dim3(512), 0, stream>>>(x, wq, wk, wv, q_r, k_n, v_n, fc, fs);
    attn_split_k<<<dim3(B * NKV * SPLIT), dim3(256), 0, stream>>>(q_r, k_n, v_n, ck, cv, p_o, p_ml);
    attn_combine<<<dim3(B * NKV), dim3(128), 0, stream>>>(p_o, p_ml, a_o);
    gemm_wo<<<dim3(256), dim3(512), 0, stream>>>(a_o, wo, outp);
}